// Round 5
// baseline (2378.932 us; speedup 1.0000x reference)
//
#include <hip/hip_runtime.h>

// HyperMixer fused kernel, MI355X (gfx950).
// x[B=2,S=4096,K=4,D=2048] f32, out[B,S,D] f32, W[24][8192] f32,
// scale[3], base[24]. Output = concat(y[B,S,K,D], collapsed[B,S,D]) f32.
//
// Round-5 design: 2 tokens per 256-thread block; wave w owns (token w>>1,
// f-half w&1). Each thread keeps its 64-elem x slice (16 float4) in
// registers for the whole kernel: phase A does all-24-row dot partials from
// regs (24 accs) against bf16 W (L2-resident), phase B transposes streams
// through a 16 KB LDS chunk buffer (4 rounds x 512 columns). W L2 traffic
// halves vs round-4 (384 KB per 2 tokens); no 32 KB x staging, no phase-A
// LDS reads. Round-4 evidence: VALUBusy 41%/HBM 19% -> W-latency bound.

#define EPS 1e-6f
constexpr int K_ = 4, D_ = 2048, KD = 8192, NOUT = 24;
constexpr int NTOK = 2 * 4096;          // 8192 tokens
constexpr int TPB = 256;

static __device__ __forceinline__ unsigned short f2bf(float f) {
    unsigned int u = __float_as_uint(f);
    unsigned int r = (u + 0x7fffu + ((u >> 16) & 1u)) >> 16;
    return (unsigned short)r;
}

__global__ void conv_w_kernel(const float* __restrict__ W, unsigned short* __restrict__ Wb) {
    int i = (blockIdx.x * blockDim.x + threadIdx.x) * 4;
    float4 v = *reinterpret_cast<const float4*>(W + i);
    ushort4 u;
    u.x = f2bf(v.x); u.y = f2bf(v.y); u.z = f2bf(v.z); u.w = f2bf(v.w);
    *reinterpret_cast<ushort4*>(Wb + i) = u;
}

template <bool BW>
__global__ __launch_bounds__(TPB, 3) void hypermix_kernel(
    const float* __restrict__ x, const float* __restrict__ outp,
    const unsigned short* __restrict__ Wb, const float* __restrict__ Wf,
    const float* __restrict__ scale, const float* __restrict__ base,
    float* __restrict__ y, float* __restrict__ coll)
{
    const int t = threadIdx.x;
    const int w = t >> 6, lane = t & 63;
    const int tok = w >> 1;            // token within block
    const int half = w & 1;            // f-half this wave owns
    const size_t gtok = (size_t)blockIdx.x * 2 + tok;

    __shared__ float xch[2][4][2][256];   // 16 KB transpose buffer [tok][k][s2][d%256]
    __shared__ float red[4][25];          // per-wave partials (24 dots + sumsq)
    __shared__ float lg[2][25];           // per-token raw dots + sumsq
    __shared__ float wts[2][24];          // 0..3 pre, 4..7 post, 8..23 comb[h][k]

    // ---- phase 0: x half -> registers, sumsq ----
    float4 xr[16];
    {
        const float* xbase = x + gtok * KD + half * 4096 + lane * 4;
        float ss = 0.f;
#pragma unroll
        for (int s = 0; s < 16; ++s) {
            float4 v = *reinterpret_cast<const float4*>(xbase + s * 256);
            xr[s] = v;
            ss += v.x * v.x + v.y * v.y + v.z * v.z + v.w * v.w;
        }
#pragma unroll
        for (int m = 1; m < 64; m <<= 1) ss += __shfl_xor(ss, m, 64);
        if (lane == 0) red[w][24] = ss;
    }

    // ---- phase A: all 24 dot rows, partial over this wave's f-half ----
    {
        float acc[24];
#pragma unroll
        for (int o = 0; o < 24; ++o) acc[o] = 0.f;
#pragma unroll
        for (int s = 0; s < 16; ++s) {
            const float4 xv = xr[s];
            const int f = half * 4096 + lane * 4 + s * 256;
#pragma unroll
            for (int o = 0; o < 24; ++o) {
                float wx, wy, wz, ww;
                if (BW) {
                    uint2 u = *reinterpret_cast<const uint2*>(Wb + o * KD + f);
                    wx = __uint_as_float(u.x << 16);
                    wy = __uint_as_float(u.x & 0xffff0000u);
                    wz = __uint_as_float(u.y << 16);
                    ww = __uint_as_float(u.y & 0xffff0000u);
                } else {
                    float4 wv = *reinterpret_cast<const float4*>(Wf + o * KD + f);
                    wx = wv.x; wy = wv.y; wz = wv.z; ww = wv.w;
                }
                acc[o] += xv.x * wx + xv.y * wy + xv.z * wz + xv.w * ww;
            }
        }
#pragma unroll
        for (int o = 0; o < 24; ++o) {
            float v = acc[o];
#pragma unroll
            for (int m = 1; m < 64; m <<= 1) v += __shfl_xor(v, m, 64);
            if (lane == 0) red[w][o] = v;
        }
    }
    __syncthreads();

    if (t < 50) {
        const int tk = t < 25 ? 0 : 1, o = t < 25 ? t : t - 25;
        lg[tk][o] = red[2 * tk][o] + red[2 * tk + 1][o];
    }
    __syncthreads();

    // ---- weights: 32 lanes (16 per token), sigmoid/softmax/sinkhorn ----
    if (t < 32) {
        const int tk = t >> 4, idx = t & 15;     // idx = h*4 + k
        float rms = rsqrtf(lg[tk][24] * (1.f / 8192.f) + EPS);
        float s0 = scale[0], s1 = scale[1], s2 = scale[2];
        float cl = lg[tk][8 + idx] * rms * s2 + base[8 + idx];
        float mx = fmaxf(cl, __shfl_xor(cl, 1, 64));
        mx = fmaxf(mx, __shfl_xor(mx, 2, 64));
        float e = expf(cl - mx);
        float se = e + __shfl_xor(e, 1, 64); se += __shfl_xor(se, 2, 64);
        float m = e / se + EPS;
        float cs = m + __shfl_xor(m, 4, 64); cs += __shfl_xor(cs, 8, 64);
        m = m / (cs + EPS);
#pragma unroll
        for (int it = 0; it < 19; ++it) {
            float rs = m + __shfl_xor(m, 1, 64); rs += __shfl_xor(rs, 2, 64);
            m = m / (rs + EPS);
            cs = m + __shfl_xor(m, 4, 64); cs += __shfl_xor(cs, 8, 64);
            m = m / (cs + EPS);
        }
        wts[tk][8 + idx] = m;
        if (idx < 4) {
            float z = lg[tk][idx] * rms * s0 + base[idx];
            wts[tk][idx] = 1.f / (1.f + expf(-z)) + EPS;
        } else if (idx < 8) {
            float z = lg[tk][idx] * rms * s1 + base[idx];
            wts[tk][idx] = 2.f / (1.f + expf(-z));
        }
    }
    __syncthreads();

    // ---- phase B: chunk transpose + outputs ----
    // Wave w writes rows h0, h0+1 of its token; half==0 waves also write coll.
    const int h0 = half * 2;
    float pre[4], postA, postB, cA[4], cB[4];
#pragma unroll
    for (int k = 0; k < 4; ++k) {
        pre[k] = wts[tok][k];
        cA[k] = wts[tok][8 + h0 * 4 + k];
        cB[k] = wts[tok][8 + (h0 + 1) * 4 + k];
    }
    postA = wts[tok][4 + h0];
    postB = wts[tok][4 + h0 + 1];

    const int k0 = 2 * half;
    float* ybase = y + gtok * KD;
    const float* obase = outp + gtok * D_;
    float* cbase = coll + gtok * D_;

#pragma unroll
    for (int r = 0; r < 4; ++r) {
        // this wave's xr subs carrying d in [r*512, r*512+512):
        // k=k0: s = 2r, 2r+1 ; k=k0+1: s = 8+2r, 8+2r+1
        *reinterpret_cast<float4*>(&xch[tok][k0][0][lane * 4])     = xr[2 * r];
        *reinterpret_cast<float4*>(&xch[tok][k0][1][lane * 4])     = xr[2 * r + 1];
        *reinterpret_cast<float4*>(&xch[tok][k0 + 1][0][lane * 4]) = xr[8 + 2 * r];
        *reinterpret_cast<float4*>(&xch[tok][k0 + 1][1][lane * 4]) = xr[8 + 2 * r + 1];
        __syncthreads();
#pragma unroll
        for (int s2 = 0; s2 < 2; ++s2) {
            const int d = r * 512 + s2 * 256 + lane * 4;
            float4 xk[4];
#pragma unroll
            for (int k = 0; k < 4; ++k)
                xk[k] = *reinterpret_cast<const float4*>(&xch[tok][k][s2][lane * 4]);
            float4 ov = *reinterpret_cast<const float4*>(obase + d);
            float4 ya, yb;
            ya.x = postA * ov.x + cA[0] * xk[0].x + cA[1] * xk[1].x + cA[2] * xk[2].x + cA[3] * xk[3].x;
            ya.y = postA * ov.y + cA[0] * xk[0].y + cA[1] * xk[1].y + cA[2] * xk[2].y + cA[3] * xk[3].y;
            ya.z = postA * ov.z + cA[0] * xk[0].z + cA[1] * xk[1].z + cA[2] * xk[2].z + cA[3] * xk[3].z;
            ya.w = postA * ov.w + cA[0] * xk[0].w + cA[1] * xk[1].w + cA[2] * xk[2].w + cA[3] * xk[3].w;
            yb.x = postB * ov.x + cB[0] * xk[0].x + cB[1] * xk[1].x + cB[2] * xk[2].x + cB[3] * xk[3].x;
            yb.y = postB * ov.y + cB[0] * xk[0].y + cB[1] * xk[1].y + cB[2] * xk[2].y + cB[3] * xk[3].y;
            yb.z = postB * ov.z + cB[0] * xk[0].z + cB[1] * xk[1].z + cB[2] * xk[2].z + cB[3] * xk[3].z;
            yb.w = postB * ov.w + cB[0] * xk[0].w + cB[1] * xk[1].w + cB[2] * xk[2].w + cB[3] * xk[3].w;
            *reinterpret_cast<float4*>(ybase + h0 * D_ + d)       = ya;
            *reinterpret_cast<float4*>(ybase + (h0 + 1) * D_ + d) = yb;
            if (half == 0) {
                float4 cv;
                cv.x = pre[0] * xk[0].x + pre[1] * xk[1].x + pre[2] * xk[2].x + pre[3] * xk[3].x;
                cv.y = pre[0] * xk[0].y + pre[1] * xk[1].y + pre[2] * xk[2].y + pre[3] * xk[3].y;
                cv.z = pre[0] * xk[0].z + pre[1] * xk[1].z + pre[2] * xk[2].z + pre[3] * xk[3].z;
                cv.w = pre[0] * xk[0].w + pre[1] * xk[1].w + pre[2] * xk[2].w + pre[3] * xk[3].w;
                *reinterpret_cast<float4*>(cbase + d) = cv;
            }
        }
        __syncthreads();
    }
}

extern "C" void kernel_launch(void* const* d_in, const int* in_sizes, int n_in,
                              void* d_out, int out_size, void* d_ws, size_t ws_size,
                              hipStream_t stream) {
    const float* x     = (const float*)d_in[0];
    const float* outp  = (const float*)d_in[1];
    const float* W     = (const float*)d_in[2];
    const float* scale = (const float*)d_in[3];
    const float* base  = (const float*)d_in[4];
    float* y    = (float*)d_out;
    float* coll = y + (size_t)NTOK * KD;   // 67108864

    const size_t wb_bytes = (size_t)NOUT * KD * sizeof(unsigned short); // 384 KB
    if (ws_size >= wb_bytes) {
        unsigned short* Wb = (unsigned short*)d_ws;
        conv_w_kernel<<<NOUT * KD / (TPB * 4), TPB, 0, stream>>>(W, Wb);
        hypermix_kernel<true><<<NTOK / 2, TPB, 0, stream>>>(x, outp, Wb, W, scale, base, y, coll);
    } else {
        hypermix_kernel<false><<<NTOK / 2, TPB, 0, stream>>>(x, outp, nullptr, W, scale, base, y, coll);
    }
}

// Round 6
// 229.612 us; speedup vs baseline: 10.3607x; 10.3607x over previous
//
#include <hip/hip_runtime.h>

// HyperMixer fused kernel, MI355X (gfx950).
// x[B=2,S=4096,K=4,D=2048] f32, out[B,S,D] f32, W[24][8192] f32,
// scale[3], base[24]. Output = concat(y[B,S,K,D], collapsed[B,S,D]) f32.
//
// Round-6: round-4 skeleton (x staged in LDS — registers across barriers
// spill, see round 5) but 2 tokens per 512-thread block (halves W L2
// traffic) and 16B W loads from a PERMUTED bf16 W layout: each uint4 holds
// 8 bf16 = W[o][f..f+3] and W[o][f+256..f+259], matching two conflict-free
// ds_read_b128 of x. Wave w: token w>>2, rows (w&3)*6..+5, full K per row
// (no cross-wave dot reduction). Per-thread state: 6 accs -> ~70 VGPR.

#define EPS 1e-6f
constexpr int K_ = 4, D_ = 2048, KD = 8192, NOUT = 24;
constexpr int NTOK = 2 * 4096;          // 8192 tokens
constexpr int TPB = 512;

static __device__ __forceinline__ unsigned int f2bf(float f) {
    unsigned int u = __float_as_uint(f);
    return (u + 0x7fffu + ((u >> 16) & 1u)) >> 16;
}

// Wperm group g = (o*16 + it)*64 + lane  ->  8 bf16:
//   e0..3 = W[o][it*512 + lane*4 + 0..3], e4..7 = W[o][it*512+256+lane*4+0..3]
__global__ void conv_w_kernel(const float* __restrict__ W, unsigned int* __restrict__ Wb) {
    int g = blockIdx.x * blockDim.x + threadIdx.x;   // 24576 groups
    int o = g >> 10, rem = g & 1023;
    int it = rem >> 6, lane = rem & 63;
    const float* src = W + o * KD + it * 512 + lane * 4;
    float4 a = *reinterpret_cast<const float4*>(src);
    float4 b = *reinterpret_cast<const float4*>(src + 256);
    uint4 u;
    u.x = (f2bf(a.y) << 16) | f2bf(a.x);
    u.y = (f2bf(a.w) << 16) | f2bf(a.z);
    u.z = (f2bf(b.y) << 16) | f2bf(b.x);
    u.w = (f2bf(b.w) << 16) | f2bf(b.z);
    *reinterpret_cast<uint4*>(Wb + (size_t)g * 4) = u;
}

static __device__ __forceinline__ float blo(unsigned int v) {
    return __uint_as_float(v << 16);
}
static __device__ __forceinline__ float bhi(unsigned int v) {
    return __uint_as_float(v & 0xffff0000u);
}

template <bool BW>
__global__ __launch_bounds__(TPB) void hypermix_kernel(
    const float* __restrict__ x, const float* __restrict__ outp,
    const unsigned int* __restrict__ Wb, const float* __restrict__ Wf,
    const float* __restrict__ scale, const float* __restrict__ base,
    float* __restrict__ y, float* __restrict__ coll)
{
    const int t = threadIdx.x;
    const int w = t >> 6, lane = t & 63;
    const int tk = t >> 8;          // token this thread stages / combines
    const int t8 = t & 255;
    const size_t gt0 = (size_t)blockIdx.x * 2;

    __shared__ float xs[2][KD];     // 64 KB: both tokens
    __shared__ float ssred[8];      // per-wave sumsq partials
    __shared__ float lg[2][24];     // raw dot products
    __shared__ float wts[2][24];    // 0..3 pre, 4..7 post, 8..23 comb[h][k]

    // ---- phase 0: stage x into LDS, per-wave sumsq ----
    {
        const float* xb = x + (gt0 + tk) * KD + t8 * 4;
        float ss = 0.f;
#pragma unroll
        for (int i = 0; i < 8; ++i) {
            float4 v = *reinterpret_cast<const float4*>(xb + i * 1024);
            *reinterpret_cast<float4*>(&xs[tk][i * 1024 + t8 * 4]) = v;
            ss += v.x * v.x + v.y * v.y + v.z * v.z + v.w * v.w;
        }
#pragma unroll
        for (int m = 1; m < 64; m <<= 1) ss += __shfl_xor(ss, m, 64);
        if (lane == 0) ssred[w] = ss;
    }
    __syncthreads();

    // ---- phase A: wave w -> token w>>2, rows (w&3)*6 .. +5, full K ----
    {
        const int atk = w >> 2;
        const int obase = (w & 3) * 6;
        float acc[6];
#pragma unroll
        for (int j = 0; j < 6; ++j) acc[j] = 0.f;
        for (int it = 0; it < 16; ++it) {
            const int f = it * 512 + lane * 4;
            float4 x0 = *reinterpret_cast<const float4*>(&xs[atk][f]);
            float4 x1 = *reinterpret_cast<const float4*>(&xs[atk][f + 256]);
#pragma unroll
            for (int j = 0; j < 6; ++j) {
                if (BW) {
                    uint4 u = *reinterpret_cast<const uint4*>(
                        Wb + (size_t)(obase + j) * KD / 2 + it * 256 + lane * 4);
                    acc[j] += x0.x * blo(u.x) + x0.y * bhi(u.x)
                            + x0.z * blo(u.y) + x0.w * bhi(u.y)
                            + x1.x * blo(u.z) + x1.y * bhi(u.z)
                            + x1.z * blo(u.w) + x1.w * bhi(u.w);
                } else {
                    const float* wr = Wf + (size_t)(obase + j) * KD + f;
                    float4 w0 = *reinterpret_cast<const float4*>(wr);
                    float4 w1 = *reinterpret_cast<const float4*>(wr + 256);
                    acc[j] += x0.x * w0.x + x0.y * w0.y + x0.z * w0.z + x0.w * w0.w
                            + x1.x * w1.x + x1.y * w1.y + x1.z * w1.z + x1.w * w1.w;
                }
            }
        }
#pragma unroll
        for (int j = 0; j < 6; ++j) {
            float v = acc[j];
#pragma unroll
            for (int m = 1; m < 64; m <<= 1) v += __shfl_xor(v, m, 64);
            if (lane == 0) lg[atk][obase + j] = v;
        }
    }
    __syncthreads();

    // ---- weights: 32 lanes (16 per token), sigmoid/softmax/sinkhorn ----
    if (t < 32) {
        const int wtk = t >> 4, idx = t & 15;     // idx = h*4 + k
        float ss = ssred[wtk * 4] + ssred[wtk * 4 + 1]
                 + ssred[wtk * 4 + 2] + ssred[wtk * 4 + 3];
        float rms = rsqrtf(ss * (1.f / 8192.f) + EPS);
        float s0 = scale[0], s1 = scale[1], s2 = scale[2];
        float cl = lg[wtk][8 + idx] * rms * s2 + base[8 + idx];
        float mx = fmaxf(cl, __shfl_xor(cl, 1, 64));
        mx = fmaxf(mx, __shfl_xor(mx, 2, 64));
        float e = expf(cl - mx);
        float se = e + __shfl_xor(e, 1, 64); se += __shfl_xor(se, 2, 64);
        float m = e / se + EPS;
        float cs = m + __shfl_xor(m, 4, 64); cs += __shfl_xor(cs, 8, 64);
        m = m / (cs + EPS);
#pragma unroll
        for (int it = 0; it < 19; ++it) {
            float rs = m + __shfl_xor(m, 1, 64); rs += __shfl_xor(rs, 2, 64);
            m = m / (rs + EPS);
            cs = m + __shfl_xor(m, 4, 64); cs += __shfl_xor(cs, 8, 64);
            m = m / (cs + EPS);
        }
        wts[wtk][8 + idx] = m;
        if (idx < 4) {
            float z = lg[wtk][idx] * rms * s0 + base[idx];
            wts[wtk][idx] = 1.f / (1.f + expf(-z)) + EPS;
        } else if (idx < 8) {
            float z = lg[wtk][idx] * rms * s1 + base[idx];
            wts[wtk][idx] = 2.f / (1.f + expf(-z));
        }
    }
    __syncthreads();

    // ---- phase B: outputs from LDS x ----
    float pre[4], post[4], cmb[4][4];
#pragma unroll
    for (int k = 0; k < 4; ++k) { pre[k] = wts[tk][k]; post[k] = wts[tk][4 + k]; }
#pragma unroll
    for (int h = 0; h < 4; ++h)
#pragma unroll
        for (int k = 0; k < 4; ++k) cmb[h][k] = wts[tk][8 + h * 4 + k];

    const float* ob = outp + (gt0 + tk) * D_;
    float* yb = y + (gt0 + tk) * KD;
    float* cb = coll + (gt0 + tk) * D_;

#pragma unroll
    for (int dh = 0; dh < 2; ++dh) {
        const int d = dh * 1024 + t8 * 4;
        float4 xk[4];
#pragma unroll
        for (int k = 0; k < 4; ++k)
            xk[k] = *reinterpret_cast<const float4*>(&xs[tk][k * 2048 + d]);
        float4 ov = *reinterpret_cast<const float4*>(ob + d);
        float4 cv;
        cv.x = pre[0] * xk[0].x + pre[1] * xk[1].x + pre[2] * xk[2].x + pre[3] * xk[3].x;
        cv.y = pre[0] * xk[0].y + pre[1] * xk[1].y + pre[2] * xk[2].y + pre[3] * xk[3].y;
        cv.z = pre[0] * xk[0].z + pre[1] * xk[1].z + pre[2] * xk[2].z + pre[3] * xk[3].z;
        cv.w = pre[0] * xk[0].w + pre[1] * xk[1].w + pre[2] * xk[2].w + pre[3] * xk[3].w;
        *reinterpret_cast<float4*>(cb + d) = cv;
#pragma unroll
        for (int h = 0; h < 4; ++h) {
            float4 yv;
            yv.x = post[h] * ov.x + cmb[h][0] * xk[0].x + cmb[h][1] * xk[1].x + cmb[h][2] * xk[2].x + cmb[h][3] * xk[3].x;
            yv.y = post[h] * ov.y + cmb[h][0] * xk[0].y + cmb[h][1] * xk[1].y + cmb[h][2] * xk[2].y + cmb[h][3] * xk[3].y;
            yv.z = post[h] * ov.z + cmb[h][0] * xk[0].z + cmb[h][1] * xk[1].z + cmb[h][2] * xk[2].z + cmb[h][3] * xk[3].z;
            yv.w = post[h] * ov.w + cmb[h][0] * xk[0].w + cmb[h][1] * xk[1].w + cmb[h][2] * xk[2].w + cmb[h][3] * xk[3].w;
            *reinterpret_cast<float4*>(yb + h * D_ + d) = yv;
        }
    }
}

extern "C" void kernel_launch(void* const* d_in, const int* in_sizes, int n_in,
                              void* d_out, int out_size, void* d_ws, size_t ws_size,
                              hipStream_t stream) {
    const float* x     = (const float*)d_in[0];
    const float* outp  = (const float*)d_in[1];
    const float* W     = (const float*)d_in[2];
    const float* scale = (const float*)d_in[3];
    const float* base  = (const float*)d_in[4];
    float* y    = (float*)d_out;
    float* coll = y + (size_t)NTOK * KD;   // 67108864

    const size_t wb_bytes = (size_t)NOUT * KD * 2; // 384 KB bf16
    if (ws_size >= wb_bytes) {
        unsigned int* Wb = (unsigned int*)d_ws;
        conv_w_kernel<<<NOUT * KD / 8 / 256, 256, 0, stream>>>(W, Wb);
        hypermix_kernel<true><<<NTOK / 2, TPB, 0, stream>>>(x, outp, Wb, W, scale, base, y, coll);
    } else {
        hypermix_kernel<false><<<NTOK / 2, TPB, 0, stream>>>(x, outp, nullptr, W, scale, base, y, coll);
    }
}